// Round 2
// baseline (14.419 us; speedup 1.0000x reference)
//
#include <hip/hip_runtime.h>

#define HH 128
#define WW 128
#define NIMG 84      // B*C = 4*21
#define BAND 32      // output rows per block
#define GR (BAND + 4)

// Closed form of the reference FW loop (done fires at t=1, freezing v = s_0):
//   out = -beta + energy_pool(sigmoid(beta))
// energy_pool = separable 5-tap stencil (weights N(i,u) x N(j,v)) minus
// self term cnt*g, with N(a,b) = max(0, min(a,b,125) - max(a-2,b-2,0) + 1).
__global__ __launch_bounds__(256, 4) void crf_onestep(const float* __restrict__ beta,
                                                      float* __restrict__ out) {
    __shared__ float gL[GR][WW];   // sigmoid(beta), band rows +/-2 halo
    __shared__ float tL[GR][WW];   // row-stencil intermediate

    const int img = blockIdx.x;    // 0..83
    const int band = blockIdx.y;   // 0..3
    const int r0 = band * BAND;
    const int tid = threadIdx.x;
    const int j = tid & (WW - 1);
    const int ty = tid >> 7;       // 0..1

    const float* __restrict__ bimg = beta + (size_t)img * (HH * WW);
    float* __restrict__ oimg = out + (size_t)img * (HH * WW);

    // ---- stage g = sigmoid(beta) for image rows r0-2 .. r0+33 (clamped)
    for (int r = ty; r < GR; r += 2) {
        int i = r0 + r - 2;
        int ic = min(max(i, 0), HH - 1);   // OOB rows get weight 0 later
        float b = bimg[ic * WW + j];
        gL[r][j] = 1.0f / (1.0f + __expf(-b));
    }
    __syncthreads();

    // ---- row pass: tL[r][j] = sum_v N(j,v) g[r][v]; per-thread weights
    float wr[5];
    int jofs[5];
#pragma unroll
    for (int d = 0; d < 5; ++d) {
        int q = j + d - 2;
        int lo = max(max(j, q) - 2, 0);
        int hi = min(min(j, q), WW - 3);
        wr[d] = (float)max(0, hi - lo + 1);
        jofs[d] = min(max(q, 0), WW - 1);  // clamped; OOB taps have w=0
    }
    const float cntj = wr[2];              // N(j,j)

    for (int r = ty; r < GR; r += 2) {
        const float* row = gL[r];
        tL[r][j] = wr[0] * row[jofs[0]] + wr[1] * row[jofs[1]] +
                   wr[2] * row[jofs[2]] + wr[3] * row[jofs[3]] +
                   wr[4] * row[jofs[4]];
    }
    __syncthreads();

    // ---- column pass + closed-form output
    for (int r = ty; r < BAND; r += 2) {
        int i = r0 + r;
        float colsum = 0.0f;
        float ci = 3.0f;                   // N(i,i)
#pragma unroll
        for (int d = 0; d < 5; ++d) {
            int u = i + d - 2;
            int lo = max(max(i, u) - 2, 0);
            int hi = min(min(i, u), HH - 3);
            float w = (float)max(0, hi - lo + 1);
            if (d == 2) ci = w;
            colsum += w * tL[r + d][j];    // staged row for u is r+d
        }
        float g = gL[r + 2][j];            // staged row for i is r+2
        float E = colsum - ci * cntj * g;  // energy_pool(sigmoid(beta))
        oimg[i * WW + j] = -bimg[i * WW + j] + E;  // -(beta + v1), v1 = -E
    }
}

extern "C" void kernel_launch(void* const* d_in, const int* in_sizes, int n_in,
                              void* d_out, int out_size, void* d_ws, size_t ws_size,
                              hipStream_t stream) {
    const float* beta = (const float*)d_in[0];
    float* out = (float*)d_out;
    (void)in_sizes; (void)n_in; (void)d_ws; (void)ws_size; (void)out_size;
    dim3 grid(NIMG, HH / BAND);
    crf_onestep<<<grid, 256, 0, stream>>>(beta, out);
}

// Round 3
// 10.144 us; speedup vs baseline: 1.4215x; 1.4215x over previous
//
#include <hip/hip_runtime.h>

#define HH 128
#define WW 128
#define NIMG 84      // B*C = 4*21
#define BAND 8       // output rows per block
#define GR (BAND + 4)

// Closed form of the reference FW loop (done fires at t=1, freezing v = s_0):
//   out = -beta + energy_pool(sigmoid(beta))
// energy_pool = separable 5-tap stencil (weights N(i,u) x N(j,v)) minus
// self term cnt*g, with N(a,b) = max(0, min(a,b,125) - max(a-2,b-2,0) + 1).
__global__ __launch_bounds__(256, 8) void crf_onestep(const float* __restrict__ beta,
                                                      float* __restrict__ out) {
    __shared__ float gL[GR][WW];   // sigmoid(beta), band rows +/-2 halo (6 KB)
    __shared__ float tL[GR][WW];   // row-stencil intermediate (6 KB)

    const int img = blockIdx.x;    // 0..83
    const int band = blockIdx.y;   // 0..15
    const int r0 = band * BAND;
    const int tid = threadIdx.x;
    const int j = tid & (WW - 1);
    const int ty = tid >> 7;       // 0..1

    const float* __restrict__ bimg = beta + (size_t)img * (HH * WW);
    float* __restrict__ oimg = out + (size_t)img * (HH * WW);

    // ---- stage g = sigmoid(beta) for staged rows r' = 0..11  (image rows
    // r0-2 .. r0+9, clamped; OOB rows get weight 0 in the column pass).
    // Thread (ty,j) stages r' = ty, ty+2, ... and keeps beta in registers.
    float breg[6];
#pragma unroll
    for (int p = 0; p < 6; ++p) {
        int r = ty + 2 * p;
        int i = r0 + r - 2;
        int ic = min(max(i, 0), HH - 1);
        float b = bimg[ic * WW + j];
        breg[p] = b;
        gL[r][j] = 1.0f / (1.0f + __expf(-b));
    }
    __syncthreads();

    // ---- row pass: tL[r][j] = sum_v N(j,v) g[r][v]; per-thread weights
    float wr[5];
    int jofs[5];
#pragma unroll
    for (int d = 0; d < 5; ++d) {
        int q = j + d - 2;
        int lo = max(max(j, q) - 2, 0);
        int hi = min(min(j, q), WW - 3);
        wr[d] = (float)max(0, hi - lo + 1);
        jofs[d] = min(max(q, 0), WW - 1);  // clamped; OOB taps have w=0
    }
    const float cntj = wr[2];              // N(j,j)

#pragma unroll
    for (int p = 0; p < 6; ++p) {
        int r = ty + 2 * p;
        const float* row = gL[r];
        tL[r][j] = wr[0] * row[jofs[0]] + wr[1] * row[jofs[1]] +
                   wr[2] * row[jofs[2]] + wr[3] * row[jofs[3]] +
                   wr[4] * row[jofs[4]];
    }
    __syncthreads();

    // ---- column pass + closed-form output (4 rows per thread)
#pragma unroll
    for (int q = 0; q < 4; ++q) {
        int r = ty + 2 * q;                // band row (staged index r+2)
        int i = r0 + r;                    // image row
        float colsum = 0.0f;
        float ci = 3.0f;                   // N(i,i)
#pragma unroll
        for (int d = 0; d < 5; ++d) {
            int u = i + d - 2;
            int lo = max(max(i, u) - 2, 0);
            int hi = min(min(i, u), HH - 3);
            float w = (float)max(0, hi - lo + 1);
            if (d == 2) ci = w;
            colsum += w * tL[r + d][j];
        }
        float g = gL[r + 2][j];
        float E = colsum - ci * cntj * g;  // energy_pool(sigmoid(beta))
        // beta(i,j) was staged as r' = r+2 -> breg[q+1] (same thread, parity ty)
        oimg[i * WW + j] = -breg[q + 1] + E;   // -(beta + v1), v1 = -E
    }
}

extern "C" void kernel_launch(void* const* d_in, const int* in_sizes, int n_in,
                              void* d_out, int out_size, void* d_ws, size_t ws_size,
                              hipStream_t stream) {
    const float* beta = (const float*)d_in[0];
    float* out = (float*)d_out;
    (void)in_sizes; (void)n_in; (void)d_ws; (void)ws_size; (void)out_size;
    dim3 grid(NIMG, HH / BAND);
    crf_onestep<<<grid, 256, 0, stream>>>(beta, out);
}